// Round 1
// baseline (228.216 us; speedup 1.0000x reference)
//
#include <hip/hip_runtime.h>
#include <stdint.h>

// RandomSampler: per-row top-k(rand*mask, k) with jax.lax.top_k semantics
// (descending score, ties -> lower index first), then gather body/mask/rule.
// Implemented as a stable per-row LSD radix sort (4x8-bit passes) on
// key_hi32 = ~bits(score) (monotone descending for non-negative floats),
// payload lo32 = in-row index. Stability gives exact jax tie-breaking.

namespace {
constexpr int kB     = 32;
constexpr int kTG    = 131072;   // 2^17
constexpr int kA     = 8;
constexpr int kK     = 16384;    // 2^14
constexpr int kTile  = 4096;
constexpr int kTiles = kTG / kTile;  // 32
constexpr int kRadix = 256;
}

__global__ void init_keys_kernel(const float* __restrict__ rnd,
                                 const float* __restrict__ msk,
                                 uint64_t* __restrict__ keys) {
    int i = blockIdx.x * blockDim.x + threadIdx.x;
    if (i >= kB * kTG) return;
    float s = rnd[i] * msk[i];                 // exact reference arithmetic
    uint32_t kb = ~__float_as_uint(s);         // ascending key == descending score
    keys[i] = ((uint64_t)kb << 32) | (uint32_t)(i & (kTG - 1));
}

__global__ void hist_kernel(const uint64_t* __restrict__ keys,
                            uint32_t* __restrict__ hist, int shift) {
    __shared__ uint32_t h[kRadix];
    int blk = blockIdx.x;                  // row * kTiles + tile
    int row = blk / kTiles;
    int t   = blk % kTiles;
    h[threadIdx.x] = 0;
    __syncthreads();
    const uint64_t* p = keys + (size_t)row * kTG + (size_t)t * kTile;
    for (int e = threadIdx.x; e < kTile; e += 256) {
        uint32_t d = (uint32_t)(p[e] >> shift) & 255u;
        atomicAdd(&h[d], 1u);
    }
    __syncthreads();
    hist[(size_t)blk * kRadix + threadIdx.x] = h[threadIdx.x];
}

// One block per row; thread b owns bin b. Produces per-(row,tile,bin) global
// scatter base offsets (digit base + prefix over earlier tiles).
__global__ void scan_kernel(const uint32_t* __restrict__ hist,
                            uint32_t* __restrict__ offs) {
    __shared__ uint32_t tot[kRadix];
    int row = blockIdx.x;
    int b = threadIdx.x;
    uint32_t sum = 0;
    for (int t = 0; t < kTiles; ++t)
        sum += hist[((size_t)row * kTiles + t) * kRadix + b];
    tot[b] = sum;
    __syncthreads();
    // Hillis-Steele inclusive scan over 256 bins
    for (int off = 1; off < kRadix; off <<= 1) {
        uint32_t v = (b >= off) ? tot[b - off] : 0u;
        __syncthreads();
        tot[b] += v;
        __syncthreads();
    }
    uint32_t run = tot[b] - sum;   // exclusive digit base within the row
    for (int t = 0; t < kTiles; ++t) {
        size_t p = ((size_t)row * kTiles + t) * kRadix + b;
        offs[p] = run;
        run += hist[p];
    }
}

// Stable ordered scatter: elements processed in tile-linear order
// (step-major, thread-minor). Within a step of 256 threads, rank among
// equal digits via per-wave ballot matching + cross-wave LDS counts.
__global__ __launch_bounds__(256) void scatter_kernel(
        const uint64_t* __restrict__ src, uint64_t* __restrict__ dst,
        const uint32_t* __restrict__ offs, int shift) {
    __shared__ uint32_t wcnt[4][kRadix];
    __shared__ uint32_t run[kRadix];
    int blk = blockIdx.x;
    int row = blk / kTiles;
    int t   = blk % kTiles;
    int tid = threadIdx.x;
    int wave = tid >> 6;
    int lane = tid & 63;
    run[tid] = offs[(size_t)blk * kRadix + tid];
    const uint64_t* p = src + (size_t)row * kTG + (size_t)t * kTile;
    uint64_t* drow = dst + (size_t)row * kTG;
    for (int step = 0; step < kTile / 256; ++step) {
        wcnt[0][tid] = 0; wcnt[1][tid] = 0; wcnt[2][tid] = 0; wcnt[3][tid] = 0;
        __syncthreads();
        uint64_t key = p[step * 256 + tid];
        uint32_t d = (uint32_t)(key >> shift) & 255u;
        // same-digit lane mask within this wave (8 ballots over digit bits)
        uint64_t m = ~0ull;
        #pragma unroll
        for (int i = 0; i < 8; ++i) {
            uint64_t bal = __ballot((int)((d >> i) & 1u));
            m &= ((d >> i) & 1u) ? bal : ~bal;
        }
        uint32_t rank = (uint32_t)__popcll(m & ((1ull << lane) - 1ull));
        if (rank == 0) wcnt[wave][d] = (uint32_t)__popcll(m);  // one leader per digit per wave
        __syncthreads();
        uint32_t before = 0;
        for (int w = 0; w < wave; ++w) before += wcnt[w][d];
        uint32_t pos = run[d] + before + rank;
        drow[pos] = key;
        __syncthreads();
        run[tid] += wcnt[0][tid] + wcnt[1][tid] + wcnt[2][tid] + wcnt[3][tid];
        // no barrier needed: next-step writes to wcnt[.][tid] are same-thread,
        // and cross-column reads resume only after the next two barriers.
    }
}

__global__ void gather_kernel(const uint64_t* __restrict__ keys,
                              const float* __restrict__ body,
                              const float* __restrict__ msk,
                              const int* __restrict__ rule,
                              int rule_is_i64,
                              float* __restrict__ out) {
    int g = blockIdx.x * blockDim.x + threadIdx.x;
    if (g >= kB * kK) return;
    int row = g >> 14;            // g / kK
    int j   = g & (kK - 1);       // g % kK
    uint64_t key = keys[(size_t)row * kTG + j];   // j-th largest score in row
    uint32_t idx = (uint32_t)(key & 0xFFFFFFFFu);
    size_t src = (size_t)row * kTG + idx;
    const float4* bp = (const float4*)(body + src * kA);
    float4* op = (float4*)(out + (size_t)g * kA);
    op[0] = bp[0];
    op[1] = bp[1];
    float* mask_out = out + (size_t)kB * kK * kA;
    float* rule_out = mask_out + (size_t)kB * kK;
    mask_out[g] = msk[src];
    int rv = rule_is_i64 ? rule[src * 2] : rule[src];  // little-endian low word
    rule_out[g] = (float)rv;
}

extern "C" void kernel_launch(void* const* d_in, const int* in_sizes, int n_in,
                              void* d_out, int out_size, void* d_ws, size_t ws_size,
                              hipStream_t stream) {
    const float* body = (const float*)d_in[0];
    const float* msk  = (const float*)d_in[1];
    const int*   rule = (const int*)d_in[2];
    const float* rnd  = (const float*)d_in[3];
    // rule_idx may arrive as int32 (JAX x64 off) or raw int64 words
    int rule_is_i64 = (in_sizes[2] == 2 * in_sizes[1]) ? 1 : 0;

    uint64_t* keys0 = (uint64_t*)d_ws;
    uint64_t* keys1 = keys0 + (size_t)kB * kTG;
    uint32_t* hist  = (uint32_t*)(keys1 + (size_t)kB * kTG);
    uint32_t* offs  = hist + (size_t)kB * kTiles * kRadix;

    init_keys_kernel<<<(kB * kTG) / 256, 256, 0, stream>>>(rnd, msk, keys0);

    uint64_t* bufs[2] = {keys0, keys1};
    int cur = 0;
    for (int pass = 0; pass < 4; ++pass) {
        int shift = 32 + 8 * pass;   // LSD over the hi-32 score key
        hist_kernel<<<kB * kTiles, 256, 0, stream>>>(bufs[cur], hist, shift);
        scan_kernel<<<kB, kRadix, 0, stream>>>(hist, offs);
        scatter_kernel<<<kB * kTiles, 256, 0, stream>>>(bufs[cur], bufs[cur ^ 1], offs, shift);
        cur ^= 1;
    }
    // after 4 passes result is back in keys0 (cur == 0)
    gather_kernel<<<(kB * kK) / 256, 256, 0, stream>>>(
        bufs[cur], body, msk, rule, rule_is_i64, (float*)d_out);
}

// Round 2
// 163.639 us; speedup vs baseline: 1.3946x; 1.3946x over previous
//
#include <hip/hip_runtime.h>
#include <stdint.h>

// RandomSampler: exact per-row top-k(rand*mask, k) with jax.lax.top_k
// semantics (descending score, ties -> lower index), then gather.
// Pruned pipeline: fine histogram -> threshold bin T -> stable compaction of
// ~16.5k candidates/row -> 3-pass stable LSD radix sort of candidates ->
// gather. Exactness: candidates = {digit <= T} superset of top-K (digit is
// monotone in key); compaction preserves index order; stable LSD over the
// only-varying key bits gives full (key asc, index asc) order == reference.

namespace {
constexpr int kB    = 32;
constexpr int kTG   = 131072;   // 2^17
constexpr int kA    = 8;
constexpr int kK    = 16384;    // 2^14
constexpr int kTilesPerRow = 8;
constexpr int kTileElems   = kTG / kTilesPerRow;   // 16384
constexpr int kHBins = 2048;
constexpr uint32_t kBaseKey = 0xC0800000u;  // key of score just below 1.0
constexpr int kCap  = 18432;    // candidate capacity per row (~16.4k expected)
}

__device__ __forceinline__ uint32_t score_key(float s) {
    return ~__float_as_uint(s);   // ascending key == descending score (s >= 0)
}
__device__ __forceinline__ uint32_t key_digit(uint32_t key) {
    // 2048 bins at full resolution over scores [0.5, 1.0); everything below
    // 0.5 (and masked zeros) clamps to bin 2047. Monotone non-decreasing.
    if (key < kBaseKey) return 0u;            // score >= 1.0 (cannot occur)
    uint32_t d = (key - kBaseKey) >> 12;
    return d > 2047u ? 2047u : d;
}

// ---------------- K1: per-(row,tile) 2048-bin histogram ----------------
__global__ __launch_bounds__(512) void hist_kernel(
        const float* __restrict__ rnd, const float* __restrict__ msk,
        uint32_t* __restrict__ hist) {
    __shared__ uint32_t h[kHBins];
    int blk = blockIdx.x;
    int r = blk >> 3, t = blk & 7;
    for (int i = threadIdx.x; i < kHBins; i += 512) h[i] = 0;
    __syncthreads();
    size_t base = (size_t)r * kTG + (size_t)t * kTileElems;
    const float4* r4 = (const float4*)(rnd + base);
    const float4* m4 = (const float4*)(msk + base);
    #pragma unroll
    for (int s = 0; s < 8; ++s) {
        int fi = s * 512 + threadIdx.x;       // float4 index within tile
        float4 a = r4[fi], b = m4[fi];
        atomicAdd(&h[key_digit(score_key(a.x * b.x))], 1u);
        atomicAdd(&h[key_digit(score_key(a.y * b.y))], 1u);
        atomicAdd(&h[key_digit(score_key(a.z * b.z))], 1u);
        atomicAdd(&h[key_digit(score_key(a.w * b.w))], 1u);
    }
    __syncthreads();
    uint32_t* out = hist + (size_t)blk * kHBins;
    for (int i = threadIdx.x; i < kHBins; i += 512) out[i] = h[i];
}

// ---------------- K2: per-row scan -> T, per-tile bases ----------------
__global__ __launch_bounds__(256) void scan_kernel(
        const uint32_t* __restrict__ hist, uint32_t* __restrict__ tilebase,
        uint32_t* __restrict__ rowT, uint32_t* __restrict__ ncand) {
    __shared__ uint32_t cum[kHBins];
    __shared__ uint32_t tsum[256];
    __shared__ uint32_t ctile[kTilesPerRow];
    __shared__ uint32_t sT;
    int r = blockIdx.x, tid = threadIdx.x;
    // row-summed histogram, thread-chunked inclusive prefix
    uint32_t v[8];
    uint32_t s = 0;
    #pragma unroll
    for (int j = 0; j < 8; ++j) {
        uint32_t b = tid * 8 + j, x = 0;
        for (int t = 0; t < kTilesPerRow; ++t)
            x += hist[((size_t)r * kTilesPerRow + t) * kHBins + b];
        s += x;
        v[j] = s;
    }
    tsum[tid] = s;
    __syncthreads();
    for (int off = 1; off < 256; off <<= 1) {
        uint32_t u = (tid >= off) ? tsum[tid - off] : 0u;
        __syncthreads();
        tsum[tid] += u;
        __syncthreads();
    }
    uint32_t excl = tsum[tid] - s;
    #pragma unroll
    for (int j = 0; j < 8; ++j) cum[tid * 8 + j] = excl + v[j];
    if (tid == 0) sT = kHBins - 1;
    __syncthreads();
    #pragma unroll
    for (int j = 0; j < 8; ++j) {
        uint32_t b = tid * 8 + j;
        uint32_t prev = (b == 0) ? 0u : cum[b - 1];
        if (cum[b] >= (uint32_t)kK && prev < (uint32_t)kK) sT = b;  // unique b
    }
    __syncthreads();
    uint32_t T = sT;
    // per-tile counts of bins <= T
    for (int t = 0; t < kTilesPerRow; ++t) {
        uint32_t part = 0;
        for (uint32_t b = tid; b <= T; b += 256)
            part += hist[((size_t)r * kTilesPerRow + t) * kHBins + b];
        tsum[tid] = part;
        __syncthreads();
        for (int off = 128; off > 0; off >>= 1) {
            if (tid < off) tsum[tid] += tsum[tid + off];
            __syncthreads();
        }
        if (tid == 0) ctile[t] = tsum[0];
        __syncthreads();
    }
    if (tid == 0) {
        uint32_t runb = 0;
        for (int t = 0; t < kTilesPerRow; ++t) {
            tilebase[r * kTilesPerRow + t] = runb;
            runb += ctile[t];
        }
        rowT[r] = T;
        ncand[r] = runb;
    }
}

// ---------------- K3: stable (index-ordered) compaction ----------------
__global__ __launch_bounds__(512) void compact_kernel(
        const float* __restrict__ rnd, const float* __restrict__ msk,
        const uint32_t* __restrict__ tilebase, const uint32_t* __restrict__ rowT,
        uint64_t* __restrict__ cand) {
    __shared__ uint32_t wtot[8];
    __shared__ uint32_t sbase;
    int blk = blockIdx.x;
    int r = blk >> 3, t = blk & 7;
    int tid = threadIdx.x, wave = tid >> 6, lane = tid & 63;
    uint32_t T = rowT[r];
    if (tid == 0) sbase = tilebase[blk];
    __syncthreads();
    size_t base = (size_t)r * kTG + (size_t)t * kTileElems;
    const float4* r4 = (const float4*)(rnd + base);
    const float4* m4 = (const float4*)(msk + base);
    uint64_t* crow = cand + (size_t)r * kCap;
    for (int s = 0; s < 8; ++s) {
        int fi = s * 512 + tid;
        float4 a = r4[fi], b = m4[fi];
        uint32_t key[4];
        bool sel[4];
        key[0] = score_key(a.x * b.x); key[1] = score_key(a.y * b.y);
        key[2] = score_key(a.z * b.z); key[3] = score_key(a.w * b.w);
        int cnt = 0;
        #pragma unroll
        for (int j = 0; j < 4; ++j) {
            sel[j] = key_digit(key[j]) <= T;
            cnt += sel[j] ? 1 : 0;
        }
        int incl = cnt;
        #pragma unroll
        for (int d = 1; d < 64; d <<= 1) {
            int u = __shfl_up(incl, d);
            if (lane >= d) incl += u;
        }
        int texcl = incl - cnt;
        if (lane == 63) wtot[wave] = (uint32_t)incl;
        __syncthreads();
        uint32_t woff = 0, rtot = 0;
        #pragma unroll
        for (int w = 0; w < 8; ++w) {
            uint32_t c = wtot[w];
            if (w < wave) woff += c;
            rtot += c;
        }
        uint32_t pos = sbase + woff + (uint32_t)texcl;
        uint32_t eidx = (uint32_t)(t * kTileElems + fi * 4);
        #pragma unroll
        for (int j = 0; j < 4; ++j)
            if (sel[j]) crow[pos++] = ((uint64_t)key[j] << 32) | (eidx + j);
        __syncthreads();
        if (tid == 0) sbase += rtot;
        __syncthreads();
    }
}

// -------- K4: per-row 3-pass stable LSD radix sort of candidates --------
// Candidate keys share bits 24..31 (span < 2^22 above kBaseKey), so sorting
// key bits 0..23 with a stable sort yields full order; compaction already
// ordered equal keys by index.
__global__ __launch_bounds__(1024) void sort_kernel(
        const uint32_t* __restrict__ ncand,
        uint64_t* __restrict__ candA, uint64_t* __restrict__ candB) {
    __shared__ uint32_t hist[256];
    __shared__ uint32_t run[256];
    __shared__ uint32_t wcnt[16][256];
    int r = blockIdx.x, tid = threadIdx.x, wave = tid >> 6, lane = tid & 63;
    uint32_t nc = ncand[r];
    if (nc > (uint32_t)kCap) nc = kCap;   // statistically unreachable
    uint64_t* A = candA + (size_t)r * kCap;
    uint64_t* Bf = candB + (size_t)r * kCap;
    for (int pass = 0; pass < 3; ++pass) {
        uint64_t* src = (pass & 1) ? Bf : A;
        uint64_t* dst = (pass & 1) ? A : Bf;
        int shift = 32 + 8 * pass;
        if (tid < 256) hist[tid] = 0;
        __syncthreads();
        for (uint32_t i = tid; i < nc; i += 1024)
            atomicAdd(&hist[(uint32_t)(src[i] >> shift) & 255u], 1u);
        __syncthreads();
        if (tid < 256) run[tid] = hist[tid];
        __syncthreads();
        for (int off = 1; off < 256; off <<= 1) {
            uint32_t u = 0;
            if (tid < 256 && tid >= off) u = run[tid - off];
            __syncthreads();
            if (tid < 256) run[tid] += u;
            __syncthreads();
        }
        if (tid < 256) run[tid] -= hist[tid];   // exclusive
        __syncthreads();
        uint32_t rounds = (nc + 1023u) / 1024u;
        for (uint32_t s = 0; s < rounds; ++s) {
            for (int i = tid; i < 16 * 256; i += 1024) ((uint32_t*)wcnt)[i] = 0;
            __syncthreads();
            uint32_t i = s * 1024u + tid;
            bool valid = i < nc;
            uint64_t v = valid ? src[i] : 0ull;
            uint32_t d = (uint32_t)(v >> shift) & 255u;
            uint64_t m = ~0ull;
            #pragma unroll
            for (int b = 0; b < 8; ++b) {
                uint64_t bal = __ballot((int)((d >> b) & 1u));
                m &= ((d >> b) & 1u) ? bal : ~bal;
            }
            m &= __ballot((int)valid);
            uint32_t rank = (uint32_t)__popcll(m & ((1ull << lane) - 1ull));
            if (valid && rank == 0) wcnt[wave][d] = (uint32_t)__popcll(m);
            __syncthreads();
            if (valid) {
                uint32_t before = 0;
                for (int w = 0; w < wave; ++w) before += wcnt[w][d];
                dst[run[d] + before + rank] = v;
            }
            __syncthreads();
            if (tid < 256) {
                uint32_t add = 0;
                #pragma unroll
                for (int w = 0; w < 16; ++w) add += wcnt[w][tid];
                run[tid] += add;
            }
            __syncthreads();
        }
        __syncthreads();
    }
}

// ---------------- K5: gather ----------------
__global__ __launch_bounds__(256) void gather_kernel(
        const uint64_t* __restrict__ cand, const float* __restrict__ body,
        const float* __restrict__ msk, const int* __restrict__ rule,
        int rule_is_i64, float* __restrict__ out) {
    int g = blockIdx.x * 256 + threadIdx.x;
    if (g >= kB * kK) return;
    int r = g >> 14, j = g & (kK - 1);
    uint32_t idx = (uint32_t)(cand[(size_t)r * kCap + j] & 0xFFFFFFFFu);
    size_t src = (size_t)r * kTG + idx;
    const float4* bp = (const float4*)(body + src * kA);
    float4* op = (float4*)(out + (size_t)g * kA);
    op[0] = bp[0];
    op[1] = bp[1];
    float* mask_out = out + (size_t)kB * kK * kA;
    float* rule_out = mask_out + (size_t)kB * kK;
    mask_out[g] = msk[src];
    int rv = rule_is_i64 ? rule[src * 2] : rule[src];
    rule_out[g] = (float)rv;
}

extern "C" void kernel_launch(void* const* d_in, const int* in_sizes, int n_in,
                              void* d_out, int out_size, void* d_ws, size_t ws_size,
                              hipStream_t stream) {
    const float* body = (const float*)d_in[0];
    const float* msk  = (const float*)d_in[1];
    const int*   rule = (const int*)d_in[2];
    const float* rnd  = (const float*)d_in[3];
    int rule_is_i64 = (in_sizes[2] == 2 * in_sizes[1]) ? 1 : 0;

    uint32_t* hist     = (uint32_t*)d_ws;                       // 32*8*2048
    uint32_t* tilebase = hist + (size_t)kB * kTilesPerRow * kHBins;
    uint32_t* rowT     = tilebase + kB * kTilesPerRow;
    uint32_t* ncand    = rowT + kB;
    size_t hdr_u32 = (size_t)kB * kTilesPerRow * kHBins + kB * kTilesPerRow + 2 * kB;
    hdr_u32 = (hdr_u32 + 1) & ~(size_t)1;                       // 8B align
    uint64_t* candA = (uint64_t*)((uint32_t*)d_ws + hdr_u32);
    uint64_t* candB = candA + (size_t)kB * kCap;

    hist_kernel<<<kB * kTilesPerRow, 512, 0, stream>>>(rnd, msk, hist);
    scan_kernel<<<kB, 256, 0, stream>>>(hist, tilebase, rowT, ncand);
    compact_kernel<<<kB * kTilesPerRow, 512, 0, stream>>>(rnd, msk, tilebase, rowT, candA);
    sort_kernel<<<kB, 1024, 0, stream>>>(ncand, candA, candB);
    gather_kernel<<<(kB * kK + 255) / 256, 256, 0, stream>>>(
        candB, body, msk, rule, rule_is_i64, (float*)d_out);
}

// Round 3
// 75.058 us; speedup vs baseline: 3.0405x; 2.1802x over previous
//
#include <hip/hip_runtime.h>
#include <stdint.h>

// RandomSampler: exact per-row top-k(rand*mask, k), jax.lax.top_k semantics
// (descending score, ties -> lower index), then gather body/mask/rule.
// Pipeline: fine 2048-bin histogram -> threshold bin T -> unordered scatter
// into per-bin segments (segments are final positions) -> per-bin wave
// bitonic sort on the u64 (key<<32|idx) value, whose unique total order
// equals (score desc, idx asc) -> gather.

namespace {
constexpr int kB    = 32;
constexpr int kTG   = 131072;   // 2^17
constexpr int kA    = 8;
constexpr int kK    = 16384;    // 2^14
constexpr int kTilesPerRow = 16;
constexpr int kTileElems   = kTG / kTilesPerRow;   // 8192
constexpr int kHBins = 2048;
constexpr uint32_t kBaseKey = 0xC0800000u;  // key of score just below 1.0
}

__device__ __forceinline__ uint32_t score_key(float s) {
    return ~__float_as_uint(s);   // ascending key == descending score (s >= 0)
}
__device__ __forceinline__ uint32_t key_digit(uint32_t key) {
    // bins 0..2046 cover scores [0.5, 1.0) at full resolution; bin 2047
    // absorbs everything below (incl. masked zeros). Monotone in key.
    if (key < kBaseKey) return 0u;
    uint32_t d = (key - kBaseKey) >> 12;
    return d > 2047u ? 2047u : d;
}

// ---------------- K1: per-(row,tile) 2048-bin histogram ----------------
__global__ __launch_bounds__(256) void hist_kernel(
        const float* __restrict__ rnd, const float* __restrict__ msk,
        uint32_t* __restrict__ hist) {
    __shared__ uint32_t h[kHBins];
    int blk = blockIdx.x;
    int r = blk >> 4, t = blk & 15;
    int tid = threadIdx.x, lane = tid & 63;
    for (int i = tid; i < kHBins; i += 256) h[i] = 0;
    __syncthreads();
    size_t base = (size_t)r * kTG + (size_t)t * kTileElems;
    const float4* r4 = (const float4*)(rnd + base);
    const float4* m4 = (const float4*)(msk + base);
    #pragma unroll
    for (int s = 0; s < 8; ++s) {
        int fi = s * 256 + tid;
        float4 a = r4[fi], b = m4[fi];
        float sc[4] = {a.x * b.x, a.y * b.y, a.z * b.z, a.w * b.w};
        #pragma unroll
        for (int j = 0; j < 4; ++j) {
            uint32_t d = key_digit(score_key(sc[j]));
            // bin 2047 takes ~55% of elements: aggregate per wave via ballot
            bool ov = (d == 2047u);
            uint64_t mb = __ballot((int)ov);
            if (ov) {
                if (lane == __ffsll((unsigned long long)mb) - 1)
                    atomicAdd(&h[2047], (uint32_t)__popcll(mb));
            } else {
                atomicAdd(&h[d], 1u);
            }
        }
    }
    __syncthreads();
    uint32_t* out = hist + (size_t)blk * kHBins;
    for (int i = tid; i < kHBins; i += 256) out[i] = h[i];
}

// -------- K2: per-row scan -> T, per-(tile,bin) scatter bases --------
__global__ __launch_bounds__(256) void scan_kernel(
        const uint32_t* __restrict__ hist, uint32_t* __restrict__ offs,
        uint32_t* __restrict__ rowT, uint32_t* __restrict__ ncand) {
    __shared__ uint32_t cum[kHBins];
    __shared__ uint32_t tsum[256];
    __shared__ uint32_t sT;
    int r = blockIdx.x, tid = threadIdx.x;
    uint32_t v[8], tot[8];
    uint32_t s = 0;
    #pragma unroll
    for (int j = 0; j < 8; ++j) {
        uint32_t b = tid * 8 + j, x = 0;
        for (int t = 0; t < kTilesPerRow; ++t)
            x += hist[((size_t)r * kTilesPerRow + t) * kHBins + b];
        tot[j] = x;
        s += x;
        v[j] = s;
    }
    tsum[tid] = s;
    __syncthreads();
    for (int off = 1; off < 256; off <<= 1) {
        uint32_t u = (tid >= off) ? tsum[tid - off] : 0u;
        __syncthreads();
        tsum[tid] += u;
        __syncthreads();
    }
    uint32_t excl = tsum[tid] - s;
    #pragma unroll
    for (int j = 0; j < 8; ++j) cum[tid * 8 + j] = excl + v[j];
    if (tid == 0) sT = kHBins - 1;
    __syncthreads();
    #pragma unroll
    for (int j = 0; j < 8; ++j) {
        uint32_t b = tid * 8 + j;
        uint32_t prev = (b == 0) ? 0u : cum[b - 1];
        if (cum[b] >= (uint32_t)kK && prev < (uint32_t)kK) sT = b;  // unique
    }
    __syncthreads();
    #pragma unroll
    for (int j = 0; j < 8; ++j) {
        uint32_t b = tid * 8 + j;
        uint32_t run = cum[b] - tot[j];   // row-exclusive base of bin b
        for (int t = 0; t < kTilesPerRow; ++t) {
            size_t p = ((size_t)r * kTilesPerRow + t) * kHBins + b;
            offs[p] = run;
            run += hist[p];
        }
    }
    if (tid == 0) {
        rowT[r] = sT;
        ncand[r] = cum[kHBins - 1];
    }
}

// ------ K3: unordered scatter of candidates into bin segments ------
__global__ __launch_bounds__(256) void scatter_kernel(
        const float* __restrict__ rnd, const float* __restrict__ msk,
        const uint32_t* __restrict__ offs, const uint32_t* __restrict__ rowT,
        uint64_t* __restrict__ cand) {
    __shared__ uint32_t run[kHBins];
    int blk = blockIdx.x;
    int r = blk >> 4, t = blk & 15;
    int tid = threadIdx.x;
    uint32_t T = rowT[r];
    for (int i = tid; i < kHBins; i += 256) run[i] = offs[(size_t)blk * kHBins + i];
    __syncthreads();
    size_t base = (size_t)r * kTG + (size_t)t * kTileElems;
    const float4* r4 = (const float4*)(rnd + base);
    const float4* m4 = (const float4*)(msk + base);
    uint64_t* crow = cand + (size_t)r * kTG;
    #pragma unroll
    for (int s = 0; s < 8; ++s) {
        int fi = s * 256 + tid;
        float4 a = r4[fi], b = m4[fi];
        uint32_t key[4];
        key[0] = score_key(a.x * b.x); key[1] = score_key(a.y * b.y);
        key[2] = score_key(a.z * b.z); key[3] = score_key(a.w * b.w);
        uint32_t eidx = (uint32_t)(t * kTileElems + fi * 4);
        #pragma unroll
        for (int j = 0; j < 4; ++j) {
            uint32_t d = key_digit(key[j]);
            if (d <= T) {   // within-bin placement order irrelevant (sorted later)
                uint32_t pos = atomicAdd(&run[d], 1u);
                crow[pos] = ((uint64_t)key[j] << 32) | (eidx + j);
            }
        }
    }
}

// ------ K4: per-bin wave bitonic sort (unique u64 order == reference) ------
__device__ __forceinline__ uint64_t cswap(uint64_t v, int j, bool dir, int lane) {
    uint64_t pv = (uint64_t)__shfl_xor((long long)v, j);
    uint64_t mn = v < pv ? v : pv;
    uint64_t mx = v < pv ? pv : v;
    bool lower = (lane & j) == 0;
    return (lower == dir) ? mn : mx;
}

__global__ __launch_bounds__(256) void binsort_kernel(
        const uint32_t* __restrict__ offs, const uint32_t* __restrict__ rowT,
        const uint32_t* __restrict__ ncand, uint64_t* __restrict__ cand) {
    int g = blockIdx.x * 4 + (threadIdx.x >> 6);   // one wave per (row,bin)
    int lane = threadIdx.x & 63;
    int r = g >> 11, b = g & 2047;
    if (b > (int)rowT[r]) return;                  // wave-uniform exit
    uint32_t start = offs[((size_t)r * kTilesPerRow) * kHBins + b];
    uint32_t end = (b + 1 < kHBins)
                 ? offs[((size_t)r * kTilesPerRow) * kHBins + b + 1]
                 : ncand[r];
    uint32_t L = end - start;
    if (L <= 1u) return;
    uint64_t* seg = cand + (size_t)r * kTG + start;
    if (L <= 64u) {
        uint64_t v = (lane < (int)L) ? seg[lane] : ~0ull;
        for (int k = 2; k <= 64; k <<= 1) {
            bool dir = ((lane & k) == 0);
            for (int j = k >> 1; j > 0; j >>= 1) v = cswap(v, j, dir, lane);
        }
        if (lane < (int)L) seg[lane] = v;
    } else if (L <= 128u) {
        uint64_t a = (lane < (int)L) ? seg[lane] : ~0ull;
        uint64_t c = (lane + 64 < (int)L) ? seg[lane + 64] : ~0ull;
        for (int k = 2; k <= 64; k <<= 1) {
            bool dA = ((lane & k) == 0);
            bool dC = (((lane + 64) & k) == 0);
            for (int j = k >> 1; j > 0; j >>= 1) {
                a = cswap(a, j, dA, lane);
                c = cswap(c, j, dC, lane);
            }
        }
        {   // k = 128 merge: j = 64 is the cross-register local exchange
            uint64_t mn = a < c ? a : c, mx = a < c ? c : a;
            a = mn; c = mx;
            for (int j = 32; j > 0; j >>= 1) {
                a = cswap(a, j, true, lane);
                c = cswap(c, j, true, lane);
            }
        }
        if (lane < (int)L) seg[lane] = a;
        if (lane + 64 < (int)L) seg[lane + 64] = c;
    } else if (lane == 0) {
        // statistically unreachable fallback: serial insertion sort
        for (uint32_t i = 1; i < L; ++i) {
            uint64_t v = seg[i];
            int j = (int)i - 1;
            while (j >= 0 && seg[j] > v) { seg[j + 1] = seg[j]; --j; }
            seg[j + 1] = v;
        }
    }
}

// ---------------- K5: gather ----------------
__global__ __launch_bounds__(256) void gather_kernel(
        const uint64_t* __restrict__ cand, const float* __restrict__ body,
        const float* __restrict__ msk, const int* __restrict__ rule,
        int rule_is_i64, float* __restrict__ out) {
    int g = blockIdx.x * 256 + threadIdx.x;
    if (g >= kB * kK) return;
    int r = g >> 14, j = g & (kK - 1);
    uint32_t idx = (uint32_t)(cand[(size_t)r * kTG + j] & 0xFFFFFFFFu);
    size_t src = (size_t)r * kTG + idx;
    const float4* bp = (const float4*)(body + src * kA);
    float4* op = (float4*)(out + (size_t)g * kA);
    op[0] = bp[0];
    op[1] = bp[1];
    float* mask_out = out + (size_t)kB * kK * kA;
    float* rule_out = mask_out + (size_t)kB * kK;
    mask_out[g] = msk[src];
    int rv = rule_is_i64 ? rule[src * 2] : rule[src];
    rule_out[g] = (float)rv;
}

extern "C" void kernel_launch(void* const* d_in, const int* in_sizes, int n_in,
                              void* d_out, int out_size, void* d_ws, size_t ws_size,
                              hipStream_t stream) {
    const float* body = (const float*)d_in[0];
    const float* msk  = (const float*)d_in[1];
    const int*   rule = (const int*)d_in[2];
    const float* rnd  = (const float*)d_in[3];
    int rule_is_i64 = (in_sizes[2] == 2 * in_sizes[1]) ? 1 : 0;

    uint32_t* hist  = (uint32_t*)d_ws;                        // 32*16*2048
    uint32_t* offs  = hist + (size_t)kB * kTilesPerRow * kHBins;
    uint32_t* rowT  = offs + (size_t)kB * kTilesPerRow * kHBins;
    uint32_t* ncand = rowT + kB;
    size_t hdr_u32 = 2 * (size_t)kB * kTilesPerRow * kHBins + 2 * kB;
    hdr_u32 = (hdr_u32 + 1) & ~(size_t)1;                     // 8B align
    uint64_t* cand = (uint64_t*)((uint32_t*)d_ws + hdr_u32);  // 32*131072 u64

    hist_kernel<<<kB * kTilesPerRow, 256, 0, stream>>>(rnd, msk, hist);
    scan_kernel<<<kB, 256, 0, stream>>>(hist, offs, rowT, ncand);
    scatter_kernel<<<kB * kTilesPerRow, 256, 0, stream>>>(rnd, msk, offs, rowT, cand);
    binsort_kernel<<<kB * kHBins / 4, 256, 0, stream>>>(offs, rowT, ncand, cand);
    gather_kernel<<<(kB * kK + 255) / 256, 256, 0, stream>>>(
        cand, body, msk, rule, rule_is_i64, (float*)d_out);
}